// Round 2
// baseline (716.918 us; speedup 1.0000x reference)
//
#include <hip/hip_runtime.h>
#include <cstddef>

#define NN    100000
#define EE    3200000
#define GG    512
#define NBKT  1563         // ceil(NN/64) fine buckets of 64 nodes
#define CAP   2432         // fine bucket capacity: mean 2048, +8.5 sigma
#define CBINS 49           // coarse bins of 2048 nodes
#define CCAP  68000        // coarse capacity: mean 65306, +10 sigma
#define TT    4096         // LDS sort tile (edges)
#define NSL   16           // channel slices (16 chans = 32B per node-slice)
#define SLB   1568         // buckets padded to multiple of 8 -> stable bucket->XCD map

typedef __attribute__((ext_vector_type(8))) short bf16x8;
typedef __attribute__((ext_vector_type(4))) float f32x4;
typedef __attribute__((ext_vector_type(8))) unsigned short u16x8;

static __device__ __forceinline__ unsigned short f2b(float f) {
  unsigned u = __float_as_uint(f);
  unsigned r = u + 0x7fffu + ((u >> 16) & 1u);   // RNE
  return (unsigned short)(r >> 16);
}
static __device__ __forceinline__ float b2f(unsigned short s) {
  return __uint_as_float(((unsigned)s) << 16);
}

// ---------------- pass 1: edges -> 49 coarse bins (LDS tile sort) ----------------
__global__ __launch_bounds__(1024, 4) void k_split1(const int* __restrict__ src,
                                                    const int* __restrict__ dst,
                                                    int* __restrict__ ccur,
                                                    int* __restrict__ cpk) {
  __shared__ int hist[CBINS], st[CBINS], cur[CBINS], gbase[CBINS];
  __shared__ int sorted[TT];
  __shared__ unsigned char binof[TT];
  const int tid  = threadIdx.x;
  const int e_lo = blockIdx.x * (EE / 256);   // 12500 edges per block
  const int e_hi = e_lo + (EE / 256);

  for (int t0 = e_lo; t0 < e_hi; t0 += TT) {
    const int tc = min(TT, e_hi - t0);
    for (int k = tid; k < CBINS; k += 1024) hist[k] = 0;
    __syncthreads();
    int myk[4], myw[4];
#pragma unroll
    for (int r = 0; r < 4; ++r) {
      int j = r * 1024 + tid;
      myk[r] = -1;
      if (j < tc) {
        int s = src[t0 + j], d = dst[t0 + j];
        myk[r] = s >> 11;                       // coarse bin
        myw[r] = ((s & 2047) << 17) | d;        // (src_local11, dst17)
        atomicAdd(&hist[myk[r]], 1);
      }
    }
    __syncthreads();
    if (tid < CBINS) {
      int s = 0;
      for (int t = 0; t < tid; ++t) s += hist[t];
      st[tid] = s; cur[tid] = s;
    }
    __syncthreads();
#pragma unroll
    for (int r = 0; r < 4; ++r) {
      if (myk[r] >= 0) {
        int pos = atomicAdd(&cur[myk[r]], 1);
        sorted[pos] = myw[r];
        binof[pos] = (unsigned char)myk[r];
      }
    }
    __syncthreads();
    if (tid < CBINS) {
      int c = cur[tid] - st[tid];
      gbase[tid] = c ? atomicAdd(&ccur[tid], c) : 0;
    }
    __syncthreads();
    for (int j = tid; j < tc; j += 1024) {
      int k = binof[j];
      int idx = gbase[k] + (j - st[k]);
      if (idx < CCAP) cpk[(size_t)k * CCAP + idx] = sorted[j];
    }
    __syncthreads();
  }
}

// ---------------- pass 2: coarse bin -> 32 fine buckets (LDS tile sort) ---------
__global__ __launch_bounds__(1024, 4) void k_split2(const int* __restrict__ ccur,
                                                    const int* __restrict__ cpk,
                                                    int* __restrict__ gcur,
                                                    int* __restrict__ pk) {
  __shared__ int hist[32], st[32], cur[32], gbase[32];
  __shared__ int sorted[TT];
  __shared__ unsigned char binof[TT];
  const int tid  = threadIdx.x;
  const int c    = blockIdx.x >> 4;            // 49 coarse bins x 16 slices
  const int sl   = blockIdx.x & 15;
  const int clen = min(ccur[c], CCAP);
  const int lo   = (int)((long long)clen * sl / 16);
  const int hi   = (int)((long long)clen * (sl + 1) / 16);
  const int* __restrict__ cp = cpk + (size_t)c * CCAP;

  for (int t0 = lo; t0 < hi; t0 += TT) {
    const int tc = min(TT, hi - t0);
    if (tid < 32) hist[tid] = 0;
    __syncthreads();
    int myk[4], myw[4];
#pragma unroll
    for (int r = 0; r < 4; ++r) {
      int j = r * 1024 + tid;
      myk[r] = -1;
      if (j < tc) {
        int w    = cp[t0 + j];
        int sl11 = w >> 17;
        myk[r] = sl11 >> 6;                      // fine bucket within coarse
        myw[r] = ((sl11 & 63) << 17) | (w & 0x1FFFF);
        atomicAdd(&hist[myk[r]], 1);
      }
    }
    __syncthreads();
    if (tid < 32) {
      int s = 0;
      for (int t = 0; t < tid; ++t) s += hist[t];
      st[tid] = s; cur[tid] = s;
    }
    __syncthreads();
#pragma unroll
    for (int r = 0; r < 4; ++r) {
      if (myk[r] >= 0) {
        int pos = atomicAdd(&cur[myk[r]], 1);
        sorted[pos] = myw[r];
        binof[pos] = (unsigned char)myk[r];
      }
    }
    __syncthreads();
    if (tid < 32) {
      int cnum = cur[tid] - st[tid];
      gbase[tid] = cnum ? atomicAdd(&gcur[c * 32 + tid], cnum) : 0;
    }
    __syncthreads();
    for (int j = tid; j < tc; j += 1024) {
      int k   = binof[j];
      int idx = gbase[k] + (j - st[k]);
      if (idx < CAP) pk[(size_t)(c * 32 + k) * CAP + idx] = sorted[j];
    }
    __syncthreads();
  }
}

// ---------------- per-bucket prep: node-grouped csr + offsets + y (SLICE-MAJOR) --
// ysl layout: [NSL][NN][16 chans] bf16 -> one slice = 3.2MB, fits per-XCD L2.
__global__ __launch_bounds__(512) void k_prep(const int* __restrict__ gcur,
                                              const int* __restrict__ pk,
                                              const float* __restrict__ x,
                                              const float* __restrict__ w1,
                                              unsigned short* __restrict__ ysl,
                                              unsigned short* __restrict__ wbf,
                                              int* __restrict__ csr,
                                              int* __restrict__ ro) {
  __shared__ int hist[64], start[65], cur[64];
  const int tid = threadIdx.x;
  const int b   = blockIdx.x;
  const int n0  = b * 64;

  if (tid < 64) hist[tid] = 0;
  __syncthreads();
  const int szc = min(gcur[b], CAP);
  for (int j = tid; j < szc; j += 512)
    atomicAdd(&hist[pk[b * CAP + j] >> 17], 1);
  __syncthreads();
  if (tid < 64) {
    int s = 0;
    for (int t = 0; t < tid; ++t) s += hist[t];
    start[tid] = s; cur[tid] = s;
    if (tid == 63) start[64] = s + hist[63];
  }
  __syncthreads();
  for (int j = tid; j < szc; j += 512) {
    int w = pk[b * CAP + j];
    int pos = atomicAdd(&cur[w >> 17], 1);
    csr[b * CAP + pos] = w & 0x1FFFF;
  }
  if (tid < 65) ro[b * 65 + tid] = start[tid];

  for (int it = 0; it < 8; ++it) {
    int idx = it * 512 + tid;          // 64 rows x 64 float4
    int row = idx >> 6, c4 = idx & 63;
    int n = n0 + row;
    if (n < NN) {
      float nr = rsqrtf((float)hist[row]);
      float4 v = ((const float4*)x)[(size_t)n * 64 + c4];
      ushort4 o;
      o.x = f2b(nr * v.x); o.y = f2b(nr * v.y); o.z = f2b(nr * v.z); o.w = f2b(nr * v.w);
      // slice-major: slice = c4>>2, within-slice ushort4 index = c4&3
      ((ushort4*)ysl)[((size_t)(c4 >> 2) * NN + n) * 4 + (c4 & 3)] = o;
    }
  }
  if (b < 64 && tid < 256) {           // W1 -> bf16
    int i = b * 256 + tid;
    float4 v = ((const float4*)w1)[i];
    ushort4 o;
    o.x = f2b(v.x); o.y = f2b(v.y); o.z = f2b(v.z); o.w = f2b(v.w);
    ((ushort4*)wbf)[i] = o;
  }
}

// ---------------- slice-phased gather: agg[n, slice] = ni*(self + sum_dst) ------
// Grid = NSL x SLB (slice outer) so all XCDs stream ONE 3.2MB slice at a time ->
// the 32x reuse is served from per-XCD L2 instead of Infinity Cache. csr staged
// in LDS; 2 lanes per node (32B/edge); agg stores nontemporal (don't evict slice).
__global__ __launch_bounds__(128, 8) void k_gath(const int* __restrict__ ro,
                                                 const int* __restrict__ csr,
                                                 const unsigned short* __restrict__ ysl,
                                                 unsigned short* __restrict__ agg) {
  __shared__ int cl[CAP];
  __shared__ int rs[65];
  const int sb = blockIdx.x;
  const int s  = sb / SLB;
  const int b  = sb - s * SLB;
  if (b >= NBKT) return;                      // padding blocks (XCD-map stability)
  const int tid = threadIdx.x;
  const int total = ro[b * 65 + 64];
  if (tid < 65) rs[tid] = ro[b * 65 + tid];
  for (int j = tid; j < total; j += 128) cl[j] = csr[(size_t)b * CAP + j];
  __syncthreads();

  const int r = tid >> 1, half = tid & 1;     // 2 lanes per node
  const int n = b * 64 + r;
  if (n >= NN) return;                        // last bucket partial (no barriers after)
  const size_t sbase = (size_t)s * NN;
  const u16x8* __restrict__ Y = (const u16x8*)ysl;   // node-slice = 2 x u16x8

  const int e0 = rs[r], e1 = rs[r + 1];
  const float ni = rsqrtf((float)(e1 - e0));
  u16x8 sv = Y[(sbase + n) * 2 + half];       // self term
  float acc[8];
#pragma unroll
  for (int c = 0; c < 8; ++c) acc[c] = b2f(sv[c]);

  int e = e0;
  for (; e + 4 <= e1; e += 4) {
    int d0 = cl[e], d1 = cl[e + 1], d2 = cl[e + 2], d3 = cl[e + 3];
    u16x8 v0 = Y[(sbase + d0) * 2 + half];
    u16x8 v1 = Y[(sbase + d1) * 2 + half];
    u16x8 v2 = Y[(sbase + d2) * 2 + half];
    u16x8 v3 = Y[(sbase + d3) * 2 + half];
#pragma unroll
    for (int c = 0; c < 8; ++c)
      acc[c] += (b2f(v0[c]) + b2f(v1[c])) + (b2f(v2[c]) + b2f(v3[c]));
  }
  for (; e < e1; ++e) {
    u16x8 v = Y[(sbase + cl[e]) * 2 + half];
#pragma unroll
    for (int c = 0; c < 8; ++c) acc[c] += b2f(v[c]);
  }
  u16x8 o;
#pragma unroll
  for (int c = 0; c < 8; ++c) o[c] = f2b(ni * acc[c]);
  __builtin_nontemporal_store(o, (u16x8*)agg + ((size_t)n * 32 + s * 2 + half));
}

// ---------------- MFMA + relu + per-graph pool over agg ------------------------
__global__ __launch_bounds__(512, 4) void k_mm(const unsigned short* __restrict__ agg,
                                               const unsigned short* __restrict__ wbf,
                                               const float* __restrict__ b1,
                                               const int* __restrict__ batch,
                                               int* __restrict__ pooled) {
  __shared__ int bg[16];
  const int tid  = threadIdx.x;
  const int n0   = blockIdx.x * 16;            // 6250 * 16 = 100000 exact
  const int wave = tid >> 6;
  const int lane = tid & 63;
  if (tid < 16) bg[tid] = batch[n0 + tid];
  __syncthreads();

  const int r16 = lane & 15, quad = lane >> 4;
  bf16x8 af[8];
#pragma unroll
  for (int kc = 0; kc < 8; ++kc)
    af[kc] = *(const bf16x8*)(agg + (size_t)(n0 + r16) * 256 + kc * 32 + quad * 8);

  f32x4 acc4[2];
#pragma unroll
  for (int t = 0; t < 2; ++t) acc4[t] = (f32x4){0.f, 0.f, 0.f, 0.f};
#pragma unroll
  for (int kc = 0; kc < 8; ++kc) {
#pragma unroll
    for (int ct = 0; ct < 2; ++ct) {
      const int nw = wave * 32 + ct * 16 + r16;
      bf16x8 bf = *(const bf16x8*)(wbf + (size_t)nw * 256 + kc * 32 + quad * 8);
      acc4[ct] = __builtin_amdgcn_mfma_f32_16x16x32_bf16(af[kc], bf, acc4[ct], 0, 0, 0);
    }
  }

  // ---- epilogue: bias + relu + per-graph column max + atomicMax ----
  const int g0 = bg[0], g15 = bg[15];
  if (g0 == g15) {
#pragma unroll
    for (int ct = 0; ct < 2; ++ct) {
      const int col = wave * 32 + ct * 16 + r16;
      const float bias = b1[col];
      float m = 0.f;   // relu identity
#pragma unroll
      for (int r = 0; r < 4; ++r) m = fmaxf(m, acc4[ct][r] + bias);
      m = fmaxf(m, __shfl_xor(m, 16, 64));
      m = fmaxf(m, __shfl_xor(m, 32, 64));
      if (quad == 0) atomicMax(&pooled[g0 * 256 + col], __float_as_int(m));
    }
  } else {
#pragma unroll
    for (int ct = 0; ct < 2; ++ct) {
      const int col = wave * 32 + ct * 16 + r16;
      const float bias = b1[col];
      for (int g = g0; g <= g15; ++g) {
        float m = 0.f;
#pragma unroll
        for (int r = 0; r < 4; ++r) {
          const int row = quad * 4 + r;
          float v = fmaxf(acc4[ct][r] + bias, 0.f);
          if (bg[row] == g) m = fmaxf(m, v);
        }
        m = fmaxf(m, __shfl_xor(m, 16, 64));
        m = fmaxf(m, __shfl_xor(m, 32, 64));
        if (quad == 0) atomicMax(&pooled[g * 256 + col], __float_as_int(m));
      }
    }
  }
}

// ---------------- out = pooled @ W2^T + b2 ----------------
__global__ void k_out(const float* __restrict__ pooled, const float* __restrict__ w2,
                      const float* __restrict__ b2, float* __restrict__ out) {
  const int wave = threadIdx.x >> 6;
  const int lane = threadIdx.x & 63;
  const int g = blockIdx.x * 4 + wave;
  float4 p = ((const float4*)pooled)[g * 64 + lane];
  float4 w = ((const float4*)w2)[lane];
  float s = p.x * w.x + p.y * w.y + p.z * w.z + p.w * w.w;
  for (int off = 32; off; off >>= 1) s += __shfl_down(s, off, 64);
  if (lane == 0) out[g] = s + b2[0];
}

extern "C" void kernel_launch(void* const* d_in, const int* in_sizes, int n_in,
                              void* d_out, int out_size, void* d_ws, size_t ws_size,
                              hipStream_t stream) {
  const float* x     = (const float*)d_in[0];
  const int*   ei    = (const int*)d_in[1];
  const int*   batch = (const int*)d_in[2];
  const float* W1    = (const float*)d_in[3];
  const float* b1    = (const float*)d_in[4];
  const float* W2    = (const float*)d_in[5];
  const float* b2    = (const float*)d_in[6];
  const int* src = ei;
  const int* dst = ei + EE;
  float* out = (float*)d_out;

  // workspace carve (256B aligned)
  size_t off = 0;
  auto carve = [&](size_t bytes) -> void* {
    void* p = (char*)d_ws + off;
    off += (bytes + 255) & ~(size_t)255;
    return p;
  };
  int*   pooled = (int*)carve((size_t)GG * 256 * 4);       // fp32 bit patterns
  int*   gcur   = (int*)carve((size_t)NBKT * 4);           // fine bucket counts
  int*   ccur   = (int*)carve((size_t)CBINS * 4);          // coarse bin counts
  const size_t zlen = off;                                  // one memset covers all 3
  unsigned short* ysl = (unsigned short*)carve((size_t)NN * 256 * 2);  // slice-major y
  int*   cpk    = (int*)carve((size_t)CBINS * CCAP * 4);   // coarse-sorted edges
  int*   pk     = (int*)carve((size_t)NBKT * CAP * 4);     // fine bucket edges
  int*   csr    = (int*)carve((size_t)NBKT * CAP * 4);     // node-grouped dst lists
  int*   ro     = (int*)carve((size_t)NBKT * 65 * 4);      // per-bucket row offsets
  unsigned short* wbf = (unsigned short*)carve(256 * 256 * 2);
  unsigned short* agg = (unsigned short*)carve((size_t)NN * 256 * 2);  // aggregated rows

  hipMemsetAsync(pooled, 0, zlen, stream);   // pooled zeros (relu floor) + cursors

  k_split1<<<256,        1024, 0, stream>>>(src, dst, ccur, cpk);
  k_split2<<<CBINS * 16, 1024, 0, stream>>>(ccur, cpk, gcur, pk);
  k_prep  <<<NBKT,        512, 0, stream>>>(gcur, pk, x, W1, ysl, wbf, csr, ro);
  k_gath  <<<NSL * SLB,   128, 0, stream>>>(ro, csr, ysl, agg);
  k_mm    <<<NN / 16,     512, 0, stream>>>(agg, wbf, b1, batch, pooled);
  k_out   <<<GG / 4,      256, 0, stream>>>((const float*)pooled, W2, b2, out);
}

// Round 4
// 488.608 us; speedup vs baseline: 1.4673x; 1.4673x over previous
//
#include <hip/hip_runtime.h>
#include <cstddef>

#define NN    100000
#define EE    3200000
#define GG    512
#define NBKT  1563         // ceil(NN/64) fine buckets of 64 nodes
#define CAP   2432         // fine bucket capacity: mean 2048, +8.5 sigma
#define CBINS 49           // coarse bins of 2048 nodes
#define CCAP  68000        // coarse capacity: mean 65306, +10 sigma
#define TT    4096         // LDS sort tile (edges)

typedef __attribute__((ext_vector_type(8))) short bf16x8;
typedef __attribute__((ext_vector_type(4))) float f32x4;
typedef __attribute__((ext_vector_type(8))) unsigned short u16x8;

static __device__ __forceinline__ unsigned short f2b(float f) {
  unsigned u = __float_as_uint(f);
  unsigned r = u + 0x7fffu + ((u >> 16) & 1u);   // RNE
  return (unsigned short)(r >> 16);
}
static __device__ __forceinline__ float b2f(unsigned short s) {
  return __uint_as_float(((unsigned)s) << 16);
}
#define BL(v) b2f((unsigned short)(v))
#define BH(v) b2f((unsigned short)((v) >> 16))

// ---------------- pass 1: edges -> 49 coarse bins (LDS tile sort) ----------------
__global__ __launch_bounds__(1024, 4) void k_split1(const int* __restrict__ src,
                                                    const int* __restrict__ dst,
                                                    int* __restrict__ ccur,
                                                    int* __restrict__ cpk) {
  __shared__ int hist[CBINS], st[CBINS], cur[CBINS], gbase[CBINS];
  __shared__ int sorted[TT];
  __shared__ unsigned char binof[TT];
  const int tid  = threadIdx.x;
  const int e_lo = blockIdx.x * (EE / 256);   // 12500 edges per block
  const int e_hi = e_lo + (EE / 256);

  for (int t0 = e_lo; t0 < e_hi; t0 += TT) {
    const int tc = min(TT, e_hi - t0);
    for (int k = tid; k < CBINS; k += 1024) hist[k] = 0;
    __syncthreads();
    int myk[4], myw[4];
#pragma unroll
    for (int r = 0; r < 4; ++r) {
      int j = r * 1024 + tid;
      myk[r] = -1;
      if (j < tc) {
        int s = src[t0 + j], d = dst[t0 + j];
        myk[r] = s >> 11;                       // coarse bin
        myw[r] = ((s & 2047) << 17) | d;        // (src_local11, dst17)
        atomicAdd(&hist[myk[r]], 1);
      }
    }
    __syncthreads();
    if (tid < CBINS) {
      int s = 0;
      for (int t = 0; t < tid; ++t) s += hist[t];
      st[tid] = s; cur[tid] = s;
    }
    __syncthreads();
#pragma unroll
    for (int r = 0; r < 4; ++r) {
      if (myk[r] >= 0) {
        int pos = atomicAdd(&cur[myk[r]], 1);
        sorted[pos] = myw[r];
        binof[pos] = (unsigned char)myk[r];
      }
    }
    __syncthreads();
    if (tid < CBINS) {
      int c = cur[tid] - st[tid];
      gbase[tid] = c ? atomicAdd(&ccur[tid], c) : 0;
    }
    __syncthreads();
    for (int j = tid; j < tc; j += 1024) {
      int k = binof[j];
      int idx = gbase[k] + (j - st[k]);
      if (idx < CCAP) cpk[(size_t)k * CCAP + idx] = sorted[j];
    }
    __syncthreads();
  }
}

// ---------------- pass 2: coarse bin -> 32 fine buckets (LDS tile sort) ---------
__global__ __launch_bounds__(1024, 4) void k_split2(const int* __restrict__ ccur,
                                                    const int* __restrict__ cpk,
                                                    int* __restrict__ gcur,
                                                    int* __restrict__ pk) {
  __shared__ int hist[32], st[32], cur[32], gbase[32];
  __shared__ int sorted[TT];
  __shared__ unsigned char binof[TT];
  const int tid  = threadIdx.x;
  const int c    = blockIdx.x >> 4;            // 49 coarse bins x 16 slices
  const int sl   = blockIdx.x & 15;
  const int clen = min(ccur[c], CCAP);
  const int lo   = (int)((long long)clen * sl / 16);
  const int hi   = (int)((long long)clen * (sl + 1) / 16);
  const int* __restrict__ cp = cpk + (size_t)c * CCAP;

  for (int t0 = lo; t0 < hi; t0 += TT) {
    const int tc = min(TT, hi - t0);
    if (tid < 32) hist[tid] = 0;
    __syncthreads();
    int myk[4], myw[4];
#pragma unroll
    for (int r = 0; r < 4; ++r) {
      int j = r * 1024 + tid;
      myk[r] = -1;
      if (j < tc) {
        int w    = cp[t0 + j];
        int sl11 = w >> 17;
        myk[r] = sl11 >> 6;                      // fine bucket within coarse
        myw[r] = ((sl11 & 63) << 17) | (w & 0x1FFFF);
        atomicAdd(&hist[myk[r]], 1);
      }
    }
    __syncthreads();
    if (tid < 32) {
      int s = 0;
      for (int t = 0; t < tid; ++t) s += hist[t];
      st[tid] = s; cur[tid] = s;
    }
    __syncthreads();
#pragma unroll
    for (int r = 0; r < 4; ++r) {
      if (myk[r] >= 0) {
        int pos = atomicAdd(&cur[myk[r]], 1);
        sorted[pos] = myw[r];
        binof[pos] = (unsigned char)myk[r];
      }
    }
    __syncthreads();
    if (tid < 32) {
      int cnum = cur[tid] - st[tid];
      gbase[tid] = cnum ? atomicAdd(&gcur[c * 32 + tid], cnum) : 0;
    }
    __syncthreads();
    for (int j = tid; j < tc; j += 1024) {
      int k   = binof[j];
      int idx = gbase[k] + (j - st[k]);
      if (idx < CAP) pk[(size_t)(c * 32 + k) * CAP + idx] = sorted[j];
    }
    __syncthreads();
  }
}

// ---------------- per-bucket prep: node-grouped csr + offsets + y = deg^-1/2*x ----
__global__ __launch_bounds__(512) void k_prep(const int* __restrict__ gcur,
                                              const int* __restrict__ pk,
                                              const float* __restrict__ x,
                                              const float* __restrict__ w1,
                                              unsigned short* __restrict__ ybf,
                                              unsigned short* __restrict__ wbf,
                                              int* __restrict__ csr,
                                              int* __restrict__ ro) {
  __shared__ int hist[64], start[65], cur[64];
  const int tid = threadIdx.x;
  const int b   = blockIdx.x;
  const int n0  = b * 64;

  if (tid < 64) hist[tid] = 0;
  __syncthreads();
  const int szc = min(gcur[b], CAP);
  for (int j = tid; j < szc; j += 512)
    atomicAdd(&hist[pk[b * CAP + j] >> 17], 1);
  __syncthreads();
  if (tid < 64) {
    int s = 0;
    for (int t = 0; t < tid; ++t) s += hist[t];
    start[tid] = s; cur[tid] = s;
    if (tid == 63) start[64] = s + hist[63];
  }
  __syncthreads();
  for (int j = tid; j < szc; j += 512) {
    int w = pk[b * CAP + j];
    int pos = atomicAdd(&cur[w >> 17], 1);
    csr[b * CAP + pos] = w & 0x1FFFF;
  }
  if (tid < 65) ro[b * 65 + tid] = start[tid];

  for (int it = 0; it < 8; ++it) {
    int idx = it * 512 + tid;          // 64 rows x 64 float4
    int row = idx >> 6, c4 = idx & 63;
    int n = n0 + row;
    if (n < NN) {
      float nr = rsqrtf((float)hist[row]);
      float4 v = ((const float4*)x)[(size_t)n * 64 + c4];
      ushort4 o;
      o.x = f2b(nr * v.x); o.y = f2b(nr * v.y); o.z = f2b(nr * v.z); o.w = f2b(nr * v.w);
      ((ushort4*)ybf)[(size_t)n * 64 + c4] = o;
    }
  }
  if (b < 64 && tid < 256) {           // W1 -> bf16
    int i = b * 256 + tid;
    float4 v = ((const float4*)w1)[i];
    ushort4 o;
    o.x = f2b(v.x); o.y = f2b(v.y); o.z = f2b(v.z); o.w = f2b(v.w);
    ((ushort4*)wbf)[i] = o;
  }
}

// ---------------- fused: gather-agg -> MFMA -> relu -> pooled atomicMax -------
// Block = 16 nodes, 1024 threads, ONE NODE PER WAVE, lane = 4 chans (uint2 =
// 2 VGPR per in-flight row). 8-edge unroll keeps 8 row-loads in flight within
// the 64-VGPR cap of (1024,8) -> full occupancy AND deep MLP (the round-1/2
// structures had VGPR=32 and serialized to ~2 outstanding misses).
__global__ __launch_bounds__(1024, 8) void k_fused4(const int* __restrict__ ro,
                                                    const int* __restrict__ csr,
                                                    const unsigned short* __restrict__ ybf,
                                                    const unsigned short* __restrict__ wbf,
                                                    const float* __restrict__ b1,
                                                    const int* __restrict__ batch,
                                                    int* __restrict__ pooled) {
  __shared__ __align__(16) unsigned short As[16][264];
  __shared__ int cl[CAP];
  __shared__ int rs[17];
  __shared__ int bg[16];
  const int tid  = threadIdx.x;
  const int n0   = blockIdx.x * 16;              // 6250 blocks * 16 = 100000 exact
  const int bkt  = blockIdx.x >> 2;
  const int br   = (blockIdx.x & 3) * 16;        // bucket-local first row
  const int wave = tid >> 6;
  const int lane = tid & 63;

  if (tid < 17) rs[tid] = ro[bkt * 65 + br + tid];
  else if (tid >= 64 && tid < 80) bg[tid - 64] = batch[n0 + tid - 64];
  __syncthreads();
  const int rs0 = rs[0];
  const int tot = rs[16] - rs0;                  // <= CAP by construction
  const int* __restrict__ ce = csr + (size_t)bkt * CAP + rs0;
  for (int j = tid; j < tot; j += 1024) cl[j] = ce[j];   // stage block's edges
  __syncthreads();

  const int il = wave;                           // block-local node 0..15
  const int i  = n0 + il;
  const uint2* __restrict__ yr = (const uint2*)ybf;   // row = 64 x uint2 (4 chans)

  int eb       = rs[il] - rs0;
  const int ee = rs[il + 1] - rs0;
  const float ni = rsqrtf((float)(ee - eb));
  uint2 sv = yr[(size_t)i * 64 + lane];          // self term y_i (4 chans)
  float a0 = BL(sv.x), a1 = BH(sv.x), a2 = BL(sv.y), a3 = BH(sv.y);

  for (; eb + 8 <= ee; eb += 8) {
    int d0 = cl[eb],     d1 = cl[eb + 1], d2 = cl[eb + 2], d3 = cl[eb + 3];
    int d4 = cl[eb + 4], d5 = cl[eb + 5], d6 = cl[eb + 6], d7 = cl[eb + 7];
    uint2 v0 = yr[(size_t)d0 * 64 + lane];
    uint2 v1 = yr[(size_t)d1 * 64 + lane];
    uint2 v2 = yr[(size_t)d2 * 64 + lane];
    uint2 v3 = yr[(size_t)d3 * 64 + lane];
    uint2 v4 = yr[(size_t)d4 * 64 + lane];
    uint2 v5 = yr[(size_t)d5 * 64 + lane];
    uint2 v6 = yr[(size_t)d6 * 64 + lane];
    uint2 v7 = yr[(size_t)d7 * 64 + lane];
    a0 += ((BL(v0.x) + BL(v1.x)) + (BL(v2.x) + BL(v3.x))) +
          ((BL(v4.x) + BL(v5.x)) + (BL(v6.x) + BL(v7.x)));
    a1 += ((BH(v0.x) + BH(v1.x)) + (BH(v2.x) + BH(v3.x))) +
          ((BH(v4.x) + BH(v5.x)) + (BH(v6.x) + BH(v7.x)));
    a2 += ((BL(v0.y) + BL(v1.y)) + (BL(v2.y) + BL(v3.y))) +
          ((BL(v4.y) + BL(v5.y)) + (BL(v6.y) + BL(v7.y)));
    a3 += ((BH(v0.y) + BH(v1.y)) + (BH(v2.y) + BH(v3.y))) +
          ((BH(v4.y) + BH(v5.y)) + (BH(v6.y) + BH(v7.y)));
  }
  for (; eb + 4 <= ee; eb += 4) {
    int d0 = cl[eb], d1 = cl[eb + 1], d2 = cl[eb + 2], d3 = cl[eb + 3];
    uint2 v0 = yr[(size_t)d0 * 64 + lane];
    uint2 v1 = yr[(size_t)d1 * 64 + lane];
    uint2 v2 = yr[(size_t)d2 * 64 + lane];
    uint2 v3 = yr[(size_t)d3 * 64 + lane];
    a0 += (BL(v0.x) + BL(v1.x)) + (BL(v2.x) + BL(v3.x));
    a1 += (BH(v0.x) + BH(v1.x)) + (BH(v2.x) + BH(v3.x));
    a2 += (BL(v0.y) + BL(v1.y)) + (BL(v2.y) + BL(v3.y));
    a3 += (BH(v0.y) + BH(v1.y)) + (BH(v2.y) + BH(v3.y));
  }
  for (; eb < ee; ++eb) {
    uint2 v = yr[(size_t)cl[eb] * 64 + lane];
    a0 += BL(v.x); a1 += BH(v.x); a2 += BL(v.y); a3 += BH(v.y);
  }
  ushort4 o;
  o.x = f2b(ni * a0); o.y = f2b(ni * a1); o.z = f2b(ni * a2); o.w = f2b(ni * a3);
  *(ushort4*)&As[il][lane * 4] = o;
  __syncthreads();

  // ---- MFMA phase: wave w covers cols [w*16, w*16+16) of the 16x256 tile ----
  const int r16 = lane & 15, quad = lane >> 4;
  f32x4 acc4 = (f32x4){0.f, 0.f, 0.f, 0.f};
  for (int kc = 0; kc < 8; ++kc) {
    bf16x8 af = *(const bf16x8*)&As[r16][kc * 32 + quad * 8];
    const int n = wave * 16 + r16;
    bf16x8 bf = *(const bf16x8*)(wbf + (size_t)n * 256 + kc * 32 + quad * 8);
    acc4 = __builtin_amdgcn_mfma_f32_16x16x32_bf16(af, bf, acc4, 0, 0, 0);
  }

  // ---- epilogue: bias + relu + per-graph column max + atomicMax ----
  const int g0 = bg[0], g15 = bg[15];
  const int col = wave * 16 + r16;
  const float bias = b1[col];
  if (g0 == g15) {
    float m = 0.f;   // relu identity
#pragma unroll
    for (int r = 0; r < 4; ++r) m = fmaxf(m, acc4[r] + bias);
    m = fmaxf(m, __shfl_xor(m, 16, 64));
    m = fmaxf(m, __shfl_xor(m, 32, 64));
    if (quad == 0) atomicMax(&pooled[g0 * 256 + col], __float_as_int(m));
  } else {
    for (int g = g0; g <= g15; ++g) {
      float m = 0.f;
#pragma unroll
      for (int r = 0; r < 4; ++r) {
        const int row = quad * 4 + r;
        float v = fmaxf(acc4[r] + bias, 0.f);
        if (bg[row] == g) m = fmaxf(m, v);
      }
      m = fmaxf(m, __shfl_xor(m, 16, 64));
      m = fmaxf(m, __shfl_xor(m, 32, 64));
      if (quad == 0) atomicMax(&pooled[g * 256 + col], __float_as_int(m));
    }
  }
}

// ---------------- out = pooled @ W2^T + b2 ----------------
__global__ void k_out(const float* __restrict__ pooled, const float* __restrict__ w2,
                      const float* __restrict__ b2, float* __restrict__ out) {
  const int wave = threadIdx.x >> 6;
  const int lane = threadIdx.x & 63;
  const int g = blockIdx.x * 4 + wave;
  float4 p = ((const float4*)pooled)[g * 64 + lane];
  float4 w = ((const float4*)w2)[lane];
  float s = p.x * w.x + p.y * w.y + p.z * w.z + p.w * w.w;
  for (int off = 32; off; off >>= 1) s += __shfl_down(s, off, 64);
  if (lane == 0) out[g] = s + b2[0];
}

extern "C" void kernel_launch(void* const* d_in, const int* in_sizes, int n_in,
                              void* d_out, int out_size, void* d_ws, size_t ws_size,
                              hipStream_t stream) {
  const float* x     = (const float*)d_in[0];
  const int*   ei    = (const int*)d_in[1];
  const int*   batch = (const int*)d_in[2];
  const float* W1    = (const float*)d_in[3];
  const float* b1    = (const float*)d_in[4];
  const float* W2    = (const float*)d_in[5];
  const float* b2    = (const float*)d_in[6];
  const int* src = ei;
  const int* dst = ei + EE;
  float* out = (float*)d_out;

  // workspace carve (256B aligned)
  size_t off = 0;
  auto carve = [&](size_t bytes) -> void* {
    void* p = (char*)d_ws + off;
    off += (bytes + 255) & ~(size_t)255;
    return p;
  };
  int*   pooled = (int*)carve((size_t)GG * 256 * 4);       // fp32 bit patterns
  int*   gcur   = (int*)carve((size_t)NBKT * 4);           // fine bucket counts
  int*   ccur   = (int*)carve((size_t)CBINS * 4);          // coarse bin counts
  const size_t zlen = off;                                  // one memset covers all 3
  unsigned short* ybf = (unsigned short*)carve((size_t)NN * 256 * 2);
  int*   cpk    = (int*)carve((size_t)CBINS * CCAP * 4);   // coarse-sorted edges
  int*   pk     = (int*)carve((size_t)NBKT * CAP * 4);     // fine bucket edges
  int*   csr    = (int*)carve((size_t)NBKT * CAP * 4);     // node-grouped dst lists
  int*   ro     = (int*)carve((size_t)NBKT * 65 * 4);      // per-bucket row offsets
  unsigned short* wbf = (unsigned short*)carve(256 * 256 * 2);

  hipMemsetAsync(pooled, 0, zlen, stream);   // pooled zeros (relu floor) + cursors

  k_split1<<<256,        1024, 0, stream>>>(src, dst, ccur, cpk);
  k_split2<<<CBINS * 16, 1024, 0, stream>>>(ccur, cpk, gcur, pk);
  k_prep  <<<NBKT,        512, 0, stream>>>(gcur, pk, x, W1, ybf, wbf, csr, ro);
  k_fused4<<<NN / 16,    1024, 0, stream>>>(ro, csr, ybf, wbf, b1, batch, pooled);
  k_out   <<<GG / 4,      256, 0, stream>>>((const float*)pooled, W2, b2, out);
}

// Round 5
// 465.760 us; speedup vs baseline: 1.5392x; 1.0491x over previous
//
#include <hip/hip_runtime.h>
#include <cstddef>

#define NN    100000
#define EE    3200000
#define GG    512
#define NBK2  391          // buckets of 256 nodes (single-pass sort)
#define BCAP  9216         // bucket capacity: mean 8192, +11 sigma
#define TT    4096         // LDS sort tile (edges)

typedef __attribute__((ext_vector_type(8))) short bf16x8;
typedef __attribute__((ext_vector_type(4))) float f32x4;
typedef __attribute__((ext_vector_type(8))) unsigned short u16x8;

static __device__ __forceinline__ unsigned short f2b(float f) {
  unsigned u = __float_as_uint(f);
  unsigned r = u + 0x7fffu + ((u >> 16) & 1u);   // RNE
  return (unsigned short)(r >> 16);
}
static __device__ __forceinline__ float b2f(unsigned short s) {
  return __uint_as_float(((unsigned)s) << 16);
}

// ---------------- single-pass sort: edges -> 391 buckets of 256 nodes -----------
// LDS tile counting-sort (391 bins); per-bin runs (~10 edges) written contiguous.
// Replaces the old 2-level split (2 kernels, 2 full passes over the edge stream).
__global__ __launch_bounds__(1024, 2) void k_split(const int* __restrict__ src,
                                                   const int* __restrict__ dst,
                                                   int* __restrict__ gcur,
                                                   int* __restrict__ pk) {
  __shared__ int hist[NBK2], st[NBK2], cur[NBK2], gbase[NBK2];
  __shared__ int sc[512];
  __shared__ int sorted[TT];
  __shared__ unsigned short binof[TT];
  const int tid  = threadIdx.x;
  const int e_lo = blockIdx.x * (EE / 256);   // 12500 edges per block
  const int e_hi = e_lo + (EE / 256);

  for (int t0 = e_lo; t0 < e_hi; t0 += TT) {
    const int tc = min(TT, e_hi - t0);
    if (tid < NBK2) hist[tid] = 0;
    __syncthreads();
    int myk[4], myw[4];
#pragma unroll
    for (int r = 0; r < 4; ++r) {
      int j = r * 1024 + tid;
      myk[r] = -1;
      if (j < tc) {
        int s = src[t0 + j], d = dst[t0 + j];
        myk[r] = s >> 8;                        // bucket of 256 nodes
        myw[r] = ((s & 255) << 17) | d;         // (src_local8, dst17)
        atomicAdd(&hist[myk[r]], 1);
      }
    }
    __syncthreads();
    // Hillis-Steele inclusive scan over 512 padded bins
    if (tid < 512) sc[tid] = (tid < NBK2) ? hist[tid] : 0;
    __syncthreads();
    for (int d = 1; d < 512; d <<= 1) {
      int v = (tid < 512 && tid >= d) ? sc[tid - d] : 0;
      __syncthreads();
      if (tid < 512) sc[tid] += v;
      __syncthreads();
    }
    if (tid < NBK2) { st[tid] = tid ? sc[tid - 1] : 0; cur[tid] = st[tid]; }
    __syncthreads();
#pragma unroll
    for (int r = 0; r < 4; ++r) {
      if (myk[r] >= 0) {
        int pos = atomicAdd(&cur[myk[r]], 1);
        sorted[pos] = myw[r];
        binof[pos] = (unsigned short)myk[r];
      }
    }
    __syncthreads();
    if (tid < NBK2) {
      int c = cur[tid] - st[tid];
      gbase[tid] = c ? atomicAdd(&gcur[tid], c) : 0;
    }
    __syncthreads();
    for (int j = tid; j < tc; j += 1024) {
      int k   = binof[j];
      int idx = gbase[k] + (j - st[k]);
      if (idx < BCAP) pk[(size_t)k * BCAP + idx] = sorted[j];
    }
    __syncthreads();
  }
}

// ---------------- per-bucket prep: node-grouped csr + offsets + y = deg^-1/2*x ----
__global__ __launch_bounds__(512) void k_prep(const int* __restrict__ gcur,
                                              const int* __restrict__ pk,
                                              const float* __restrict__ x,
                                              const float* __restrict__ w1,
                                              unsigned short* __restrict__ ybf,
                                              unsigned short* __restrict__ wbf,
                                              int* __restrict__ csr,
                                              int* __restrict__ ro) {
  __shared__ int hist[256], start[257], cur[256], sc[256];
  const int tid = threadIdx.x;
  const int b   = blockIdx.x;
  const int n0  = b * 256;

  if (tid < 256) hist[tid] = 0;
  __syncthreads();
  const int szc = min(gcur[b], BCAP);
  const int* __restrict__ pb = pk + (size_t)b * BCAP;
  for (int j = tid; j < szc; j += 512)
    atomicAdd(&hist[pb[j] >> 17], 1);
  __syncthreads();
  if (tid < 256) sc[tid] = hist[tid];
  __syncthreads();
  for (int d = 1; d < 256; d <<= 1) {
    int v = (tid < 256 && tid >= d) ? sc[tid - d] : 0;
    __syncthreads();
    if (tid < 256) sc[tid] += v;
    __syncthreads();
  }
  if (tid < 256) { start[tid] = tid ? sc[tid - 1] : 0; cur[tid] = start[tid]; }
  if (tid == 0) start[256] = 0;   // patched below after scan completes
  __syncthreads();
  if (tid == 0) start[256] = sc[255];
  __syncthreads();
  for (int j = tid; j < szc; j += 512) {
    int w = pb[j];
    int pos = atomicAdd(&cur[w >> 17], 1);
    csr[(size_t)b * BCAP + pos] = w & 0x1FFFF;
  }
  if (tid < 257) ro[b * 257 + tid] = start[tid];

  for (int it = 0; it < 32; ++it) {
    int idx = it * 512 + tid;          // 256 rows x 64 float4
    int row = idx >> 6, c4 = idx & 63;
    int n = n0 + row;
    if (n < NN) {
      float nr = rsqrtf((float)(start[row + 1] - start[row]));
      float4 v = ((const float4*)x)[(size_t)n * 64 + c4];
      ushort4 o;
      o.x = f2b(nr * v.x); o.y = f2b(nr * v.y); o.z = f2b(nr * v.z); o.w = f2b(nr * v.w);
      ((ushort4*)ybf)[(size_t)n * 64 + c4] = o;
    }
  }
  if (b < 64 && tid < 256) {           // W1 -> bf16
    int i = b * 256 + tid;
    float4 v = ((const float4*)w1)[i];
    ushort4 o;
    o.x = f2b(v.x); o.y = f2b(v.y); o.z = f2b(v.z); o.w = f2b(v.w);
    ((ushort4*)wbf)[i] = o;
  }
}

// ---------------- fused: gather-agg -> MFMA -> relu -> pooled atomicMax -------
// Round-1 verified structure: block = 16 nodes, 512 threads, one node per
// half-wave, 8-edge unroll, direct csr reads (no LDS staging). Only the
// bucket geometry changed (256-node buckets, ro stride 257, csr stride BCAP).
__global__ __launch_bounds__(512, 8) void k_fused4(const int* __restrict__ ro,
                                                   const int* __restrict__ csr,
                                                   const unsigned short* __restrict__ ybf,
                                                   const unsigned short* __restrict__ wbf,
                                                   const float* __restrict__ b1,
                                                   const int* __restrict__ batch,
                                                   int* __restrict__ pooled) {
  __shared__ __align__(16) unsigned short As[16][264];
  __shared__ int rs[17];
  __shared__ int bg[16];
  const int tid  = threadIdx.x;
  const int n0   = blockIdx.x * 16;              // 6250 blocks * 16 = 100000 exact
  const int bkt  = blockIdx.x >> 4;              // 256-node bucket
  const int br   = (blockIdx.x & 15) * 16;       // bucket-local first row
  const int wave = tid >> 6;
  const int lane = tid & 63;

  if (tid < 17) rs[tid] = ro[bkt * 257 + br + tid];
  else if (tid >= 64 && tid < 80) bg[tid - 64] = batch[n0 + tid - 64];
  __syncthreads();

  const int half = lane >> 5, l32 = lane & 31;
  const int il   = wave * 2 + half;              // 0..15, block-local node
  const int i    = n0 + il;
  const u16x8* __restrict__ yr = (const u16x8*)ybf;   // row = 32 x u16x8
  const int* __restrict__ ce = csr + (size_t)bkt * BCAP;

  u16x8 sv = yr[(size_t)i * 32 + l32];           // self term y_i
  float acc[8];
#pragma unroll
  for (int c = 0; c < 8; ++c) acc[c] = b2f(sv[c]);

  int e = rs[il];
  const int e1 = rs[il + 1];
  const float ni = rsqrtf((float)(e1 - e));
  for (; e + 8 <= e1; e += 8) {
    int d0 = ce[e],     d1 = ce[e + 1], d2 = ce[e + 2], d3 = ce[e + 3];
    int d4 = ce[e + 4], d5 = ce[e + 5], d6 = ce[e + 6], d7 = ce[e + 7];
    u16x8 v0 = yr[(size_t)d0 * 32 + l32];
    u16x8 v1 = yr[(size_t)d1 * 32 + l32];
    u16x8 v2 = yr[(size_t)d2 * 32 + l32];
    u16x8 v3 = yr[(size_t)d3 * 32 + l32];
    u16x8 v4 = yr[(size_t)d4 * 32 + l32];
    u16x8 v5 = yr[(size_t)d5 * 32 + l32];
    u16x8 v6 = yr[(size_t)d6 * 32 + l32];
    u16x8 v7 = yr[(size_t)d7 * 32 + l32];
#pragma unroll
    for (int c = 0; c < 8; ++c)
      acc[c] += ((b2f(v0[c]) + b2f(v1[c])) + (b2f(v2[c]) + b2f(v3[c]))) +
                ((b2f(v4[c]) + b2f(v5[c])) + (b2f(v6[c]) + b2f(v7[c])));
  }
  for (; e + 4 <= e1; e += 4) {
    int d0 = ce[e], d1 = ce[e + 1], d2 = ce[e + 2], d3 = ce[e + 3];
    u16x8 v0 = yr[(size_t)d0 * 32 + l32];
    u16x8 v1 = yr[(size_t)d1 * 32 + l32];
    u16x8 v2 = yr[(size_t)d2 * 32 + l32];
    u16x8 v3 = yr[(size_t)d3 * 32 + l32];
#pragma unroll
    for (int c = 0; c < 8; ++c)
      acc[c] += (b2f(v0[c]) + b2f(v1[c])) + (b2f(v2[c]) + b2f(v3[c]));
  }
  for (; e < e1; ++e) {
    u16x8 v = yr[(size_t)ce[e] * 32 + l32];
#pragma unroll
    for (int c = 0; c < 8; ++c) acc[c] += b2f(v[c]);
  }
  u16x8 o;
#pragma unroll
  for (int c = 0; c < 8; ++c) o[c] = f2b(ni * acc[c]);
  *(u16x8*)&As[il][l32 * 8] = o;
  __syncthreads();

  // ---- MFMA phase: wave w covers cols [w*32, w*32+32) of the 16x256 tile ----
  const int r16 = lane & 15, quad = lane >> 4;
  f32x4 acc4[2];
#pragma unroll
  for (int t = 0; t < 2; ++t) acc4[t] = (f32x4){0.f, 0.f, 0.f, 0.f};
  for (int kc = 0; kc < 8; ++kc) {
    bf16x8 af = *(const bf16x8*)&As[r16][kc * 32 + quad * 8];
#pragma unroll
    for (int ct = 0; ct < 2; ++ct) {
      const int n = wave * 32 + ct * 16 + r16;
      bf16x8 bf = *(const bf16x8*)(wbf + (size_t)n * 256 + kc * 32 + quad * 8);
      acc4[ct] = __builtin_amdgcn_mfma_f32_16x16x32_bf16(af, bf, acc4[ct], 0, 0, 0);
    }
  }

  // ---- epilogue: bias + relu + per-graph column max + atomicMax ----
  const int g0 = bg[0], g15 = bg[15];
  if (g0 == g15) {
#pragma unroll
    for (int ct = 0; ct < 2; ++ct) {
      const int col = wave * 32 + ct * 16 + r16;
      const float bias = b1[col];
      float m = 0.f;   // relu identity
#pragma unroll
      for (int r = 0; r < 4; ++r) m = fmaxf(m, acc4[ct][r] + bias);
      m = fmaxf(m, __shfl_xor(m, 16, 64));
      m = fmaxf(m, __shfl_xor(m, 32, 64));
      if (quad == 0) atomicMax(&pooled[g0 * 256 + col], __float_as_int(m));
    }
  } else {
#pragma unroll
    for (int ct = 0; ct < 2; ++ct) {
      const int col = wave * 32 + ct * 16 + r16;
      const float bias = b1[col];
      for (int g = g0; g <= g15; ++g) {
        float m = 0.f;
#pragma unroll
        for (int r = 0; r < 4; ++r) {
          const int row = quad * 4 + r;
          float v = fmaxf(acc4[ct][r] + bias, 0.f);
          if (bg[row] == g) m = fmaxf(m, v);
        }
        m = fmaxf(m, __shfl_xor(m, 16, 64));
        m = fmaxf(m, __shfl_xor(m, 32, 64));
        if (quad == 0) atomicMax(&pooled[g * 256 + col], __float_as_int(m));
      }
    }
  }
}

// ---------------- out = pooled @ W2^T + b2 ----------------
__global__ void k_out(const float* __restrict__ pooled, const float* __restrict__ w2,
                      const float* __restrict__ b2, float* __restrict__ out) {
  const int wave = threadIdx.x >> 6;
  const int lane = threadIdx.x & 63;
  const int g = blockIdx.x * 4 + wave;
  float4 p = ((const float4*)pooled)[g * 64 + lane];
  float4 w = ((const float4*)w2)[lane];
  float s = p.x * w.x + p.y * w.y + p.z * w.z + p.w * w.w;
  for (int off = 32; off; off >>= 1) s += __shfl_down(s, off, 64);
  if (lane == 0) out[g] = s + b2[0];
}

extern "C" void kernel_launch(void* const* d_in, const int* in_sizes, int n_in,
                              void* d_out, int out_size, void* d_ws, size_t ws_size,
                              hipStream_t stream) {
  const float* x     = (const float*)d_in[0];
  const int*   ei    = (const int*)d_in[1];
  const int*   batch = (const int*)d_in[2];
  const float* W1    = (const float*)d_in[3];
  const float* b1    = (const float*)d_in[4];
  const float* W2    = (const float*)d_in[5];
  const float* b2    = (const float*)d_in[6];
  const int* src = ei;
  const int* dst = ei + EE;
  float* out = (float*)d_out;

  // workspace carve (256B aligned)
  size_t off = 0;
  auto carve = [&](size_t bytes) -> void* {
    void* p = (char*)d_ws + off;
    off += (bytes + 255) & ~(size_t)255;
    return p;
  };
  int*   pooled = (int*)carve((size_t)GG * 256 * 4);       // fp32 bit patterns
  int*   gcur   = (int*)carve((size_t)NBK2 * 4);           // bucket counts
  const size_t zlen = off;                                  // one memset covers both
  unsigned short* ybf = (unsigned short*)carve((size_t)NN * 256 * 2);
  int*   pk     = (int*)carve((size_t)NBK2 * BCAP * 4);    // bucket-sorted edges
  int*   csr    = (int*)carve((size_t)NBK2 * BCAP * 4);    // node-grouped dst lists
  int*   ro     = (int*)carve((size_t)NBK2 * 257 * 4);     // per-bucket row offsets
  unsigned short* wbf = (unsigned short*)carve(256 * 256 * 2);

  hipMemsetAsync(pooled, 0, zlen, stream);   // pooled zeros (relu floor) + cursors

  k_split<<<256,     1024, 0, stream>>>(src, dst, gcur, pk);
  k_prep <<<NBK2,     512, 0, stream>>>(gcur, pk, x, W1, ybf, wbf, csr, ro);
  k_fused4<<<NN / 16, 512, 0, stream>>>(ro, csr, ybf, wbf, b1, batch, pooled);
  k_out  <<<GG / 4,   256, 0, stream>>>((const float*)pooled, W2, b2, out);
}

// Round 6
// 441.902 us; speedup vs baseline: 1.6223x; 1.0540x over previous
//
#include <hip/hip_runtime.h>
#include <cstddef>

#define NN    100000
#define EE    3200000
#define GG    512
#define NBK2  391          // buckets of 256 nodes (single-pass sort)
#define BCAP  9216         // bucket capacity: mean 8192, +11 sigma
#define TT    4096         // LDS sort tile (edges)

typedef __attribute__((ext_vector_type(8))) short bf16x8;
typedef __attribute__((ext_vector_type(4))) float f32x4;
typedef __attribute__((ext_vector_type(8))) unsigned short u16x8;

struct U12 { unsigned a, b, c; };   // 12 B: 8 chans x 12-bit

static __device__ __forceinline__ unsigned short f2b(float f) {
  unsigned u = __float_as_uint(f);
  unsigned r = u + 0x7fffu + ((u >> 16) & 1u);   // RNE
  return (unsigned short)(r >> 16);
}

// ---------------- single-pass sort: edges -> 391 buckets, 1 tile per block -----
__global__ __launch_bounds__(1024, 2) void k_split(const int* __restrict__ src,
                                                   const int* __restrict__ dst,
                                                   int* __restrict__ gcur,
                                                   int* __restrict__ pk) {
  __shared__ int hist[NBK2], st[NBK2], cur[NBK2], gbase[NBK2];
  __shared__ int sc[512];
  __shared__ int sorted[TT];
  __shared__ unsigned short binof[TT];
  const int tid = threadIdx.x;
  const int t0  = blockIdx.x * TT;
  const int tc  = min(TT, EE - t0);

  if (tid < NBK2) hist[tid] = 0;
  __syncthreads();
  int myk[4], myw[4];
#pragma unroll
  for (int r = 0; r < 4; ++r) {
    int j = r * 1024 + tid;
    myk[r] = -1;
    if (j < tc) {
      int s = src[t0 + j], d = dst[t0 + j];
      myk[r] = s >> 8;                        // bucket of 256 nodes
      myw[r] = ((s & 255) << 17) | d;         // (src_local8, dst17)
      atomicAdd(&hist[myk[r]], 1);
    }
  }
  __syncthreads();
  if (tid < 512) sc[tid] = (tid < NBK2) ? hist[tid] : 0;
  __syncthreads();
  for (int d = 1; d < 512; d <<= 1) {
    int v = (tid < 512 && tid >= d) ? sc[tid - d] : 0;
    __syncthreads();
    if (tid < 512) sc[tid] += v;
    __syncthreads();
  }
  if (tid < NBK2) { st[tid] = tid ? sc[tid - 1] : 0; cur[tid] = st[tid]; }
  __syncthreads();
#pragma unroll
  for (int r = 0; r < 4; ++r) {
    if (myk[r] >= 0) {
      int pos = atomicAdd(&cur[myk[r]], 1);
      sorted[pos] = myw[r];
      binof[pos] = (unsigned short)myk[r];
    }
  }
  __syncthreads();
  if (tid < NBK2) {
    int c = cur[tid] - st[tid];
    gbase[tid] = c ? atomicAdd(&gcur[tid], c) : 0;
  }
  __syncthreads();
  for (int j = tid; j < tc; j += 1024) {
    int k   = binof[j];
    int idx = gbase[k] + (j - st[k]);
    if (idx < BCAP) pk[(size_t)k * BCAP + idx] = sorted[j];
  }
}

// ---------------- per-bucket prep: csr + ro + global y-absmax + W1->bf16 -------
__global__ __launch_bounds__(512) void k_prep(const int* __restrict__ gcur,
                                              const int* __restrict__ pk,
                                              const float* __restrict__ x,
                                              const float* __restrict__ w1,
                                              unsigned short* __restrict__ wbf,
                                              int* __restrict__ csr,
                                              int* __restrict__ ro,
                                              int* __restrict__ xm) {
  __shared__ int hist[256], start[257], cur[256], sc[256];
  __shared__ float red[8];
  const int tid = threadIdx.x;
  const int b   = blockIdx.x;
  const int n0  = b * 256;

  if (tid < 256) hist[tid] = 0;
  __syncthreads();
  const int szc = min(gcur[b], BCAP);
  const int* __restrict__ pb = pk + (size_t)b * BCAP;
  for (int j = tid; j < szc; j += 512)
    atomicAdd(&hist[pb[j] >> 17], 1);
  __syncthreads();
  if (tid < 256) sc[tid] = hist[tid];
  __syncthreads();
  for (int d = 1; d < 256; d <<= 1) {
    int v = (tid < 256 && tid >= d) ? sc[tid - d] : 0;
    __syncthreads();
    if (tid < 256) sc[tid] += v;
    __syncthreads();
  }
  if (tid < 256) { start[tid] = tid ? sc[tid - 1] : 0; cur[tid] = start[tid]; }
  __syncthreads();
  if (tid == 0) start[256] = sc[255];
  __syncthreads();
  for (int j = tid; j < szc; j += 512) {
    int w = pb[j];
    int pos = atomicAdd(&cur[w >> 17], 1);
    csr[(size_t)b * BCAP + pos] = w & 0x1FFFF;
  }
  if (tid < 257) ro[b * 257 + tid] = start[tid];
  __syncthreads();

  // global tight scale: s = max over rows of deg^-1/2 * max|x_row|
  float tmax = 0.f;
  for (int it = 0; it < 32; ++it) {
    int idx = it * 512 + tid;          // 256 rows x 64 float4
    int row = idx >> 6, c4 = idx & 63;
    int n = n0 + row;
    int deg = start[row + 1] - start[row];
    if (n < NN && deg > 0) {
      float nr = rsqrtf((float)deg);
      float4 v = ((const float4*)x)[(size_t)n * 64 + c4];
      float m = fmaxf(fmaxf(fabsf(v.x), fabsf(v.y)), fmaxf(fabsf(v.z), fabsf(v.w)));
      tmax = fmaxf(tmax, nr * m);
    }
  }
#pragma unroll
  for (int k = 1; k < 64; k <<= 1) tmax = fmaxf(tmax, __shfl_xor(tmax, k, 64));
  if ((tid & 63) == 0) red[tid >> 6] = tmax;
  __syncthreads();
  if (tid == 0) {
    float m = red[0];
#pragma unroll
    for (int w = 1; w < 8; ++w) m = fmaxf(m, red[w]);
    atomicMax(xm, __float_as_int(m));   // positive floats: int order == float order
  }

  if (b < 64 && tid < 256) {           // W1 -> bf16
    int i = b * 256 + tid;
    float4 v = ((const float4*)w1)[i];
    ushort4 o;
    o.x = f2b(v.x); o.y = f2b(v.y); o.z = f2b(v.z); o.w = f2b(v.w);
    ((ushort4*)wbf)[i] = o;
  }
}

// ---------------- pack: y12[n] = int12x256( deg^-1/2 * x[n] / s ) --------------
// Half-wave per row: lane = 8 chans -> 3 dwords (12 B). Full occupancy grid.
__global__ __launch_bounds__(256) void k_pack(const float* __restrict__ x,
                                              const int* __restrict__ ro,
                                              const int* __restrict__ xm,
                                              unsigned* __restrict__ y12) {
  const int tid = threadIdx.x;
  const int row = blockIdx.x * 8 + (tid >> 5);   // 12500 * 8 = 100000 exact
  const int l32 = tid & 31;
  const int bkt = row >> 8, r = row & 255;
  const int deg = ro[bkt * 257 + r + 1] - ro[bkt * 257 + r];
  const float nr  = rsqrtf((float)deg);
  const float s   = __int_as_float(*xm);
  const float inv = 2047.0f / s;

  float4 a = ((const float4*)x)[(size_t)row * 64 + l32 * 2];
  float4 b = ((const float4*)x)[(size_t)row * 64 + l32 * 2 + 1];
  int q[8];
  float v[8] = {a.x, a.y, a.z, a.w, b.x, b.y, b.z, b.w};
#pragma unroll
  for (int c = 0; c < 8; ++c) {
    int t = (int)rintf(nr * v[c] * inv) + 2048;
    q[c] = min(4095, max(0, t));
  }
  U12 o;
  o.a = (unsigned)q[0] | ((unsigned)q[1] << 12) | ((unsigned)(q[2] & 0xFF) << 24);
  o.b = ((unsigned)q[2] >> 8) | ((unsigned)q[3] << 4) | ((unsigned)q[4] << 16) |
        ((unsigned)(q[5] & 0xF) << 28);
  o.c = ((unsigned)q[5] >> 4) | ((unsigned)q[6] << 8) | ((unsigned)q[7] << 20);
  ((U12*)y12)[(size_t)row * 32 + l32] = o;
}

// ---------------- fused: int12 gather-agg -> MFMA -> relu -> pooled max --------
// Round-1 verified shape (block = 16 nodes, one node per half-wave, 8-edge
// unroll, direct csr reads). Payload now 12 B/lane/edge, EXACT integer sums.
__global__ __launch_bounds__(512, 8) void k_fused4(const int* __restrict__ ro,
                                                   const int* __restrict__ csr,
                                                   const unsigned* __restrict__ y12,
                                                   const unsigned short* __restrict__ wbf,
                                                   const float* __restrict__ b1,
                                                   const int* __restrict__ batch,
                                                   const int* __restrict__ xm,
                                                   int* __restrict__ pooled) {
  __shared__ __align__(16) unsigned short As[16][264];
  __shared__ int rs[17];
  __shared__ int bg[16];
  const int tid  = threadIdx.x;
  const int n0   = blockIdx.x * 16;              // 6250 blocks * 16 = 100000 exact
  const int bkt  = blockIdx.x >> 4;              // 256-node bucket
  const int br   = (blockIdx.x & 15) * 16;       // bucket-local first row
  const int wave = tid >> 6;
  const int lane = tid & 63;

  if (tid < 17) rs[tid] = ro[bkt * 257 + br + tid];
  else if (tid >= 64 && tid < 80) bg[tid - 64] = batch[n0 + tid - 64];
  __syncthreads();

  const int half = lane >> 5, l32 = lane & 31;
  const int il   = wave * 2 + half;              // 0..15, block-local node
  const int i    = n0 + il;
  const U12* __restrict__ yr = (const U12*)y12;  // row = 32 x 12 B
  const int* __restrict__ ce = csr + (size_t)bkt * BCAP;
  const float s = __int_as_float(*xm);

  int acc[8];
#pragma unroll
  for (int c = 0; c < 8; ++c) acc[c] = 0;
#define UNP(V) do { unsigned w0 = (V).a, w1 = (V).b, w2 = (V).c;                  \
    acc[0] += (int)(w0 & 0xFFFu);                                                 \
    acc[1] += (int)((w0 >> 12) & 0xFFFu);                                         \
    acc[2] += (int)((w0 >> 24) | ((w1 & 0xFu) << 8));                             \
    acc[3] += (int)((w1 >> 4) & 0xFFFu);                                          \
    acc[4] += (int)((w1 >> 16) & 0xFFFu);                                         \
    acc[5] += (int)((w1 >> 28) | ((w2 & 0xFFu) << 4));                            \
    acc[6] += (int)((w2 >> 8) & 0xFFFu);                                          \
    acc[7] += (int)(w2 >> 20); } while (0)

  U12 sv = yr[(size_t)i * 32 + l32];             // self term
  UNP(sv);

  int e = rs[il];
  const int e1 = rs[il + 1];
  const int cnt = e1 - e + 1;
  const float ni = rsqrtf((float)(e1 - e));
  for (; e + 8 <= e1; e += 8) {
    int d0 = ce[e],     d1 = ce[e + 1], d2 = ce[e + 2], d3 = ce[e + 3];
    int d4 = ce[e + 4], d5 = ce[e + 5], d6 = ce[e + 6], d7 = ce[e + 7];
    U12 v0 = yr[(size_t)d0 * 32 + l32];
    U12 v1 = yr[(size_t)d1 * 32 + l32];
    U12 v2 = yr[(size_t)d2 * 32 + l32];
    U12 v3 = yr[(size_t)d3 * 32 + l32];
    U12 v4 = yr[(size_t)d4 * 32 + l32];
    U12 v5 = yr[(size_t)d5 * 32 + l32];
    U12 v6 = yr[(size_t)d6 * 32 + l32];
    U12 v7 = yr[(size_t)d7 * 32 + l32];
    UNP(v0); UNP(v1); UNP(v2); UNP(v3); UNP(v4); UNP(v5); UNP(v6); UNP(v7);
  }
  for (; e + 4 <= e1; e += 4) {
    int d0 = ce[e], d1 = ce[e + 1], d2 = ce[e + 2], d3 = ce[e + 3];
    U12 v0 = yr[(size_t)d0 * 32 + l32];
    U12 v1 = yr[(size_t)d1 * 32 + l32];
    U12 v2 = yr[(size_t)d2 * 32 + l32];
    U12 v3 = yr[(size_t)d3 * 32 + l32];
    UNP(v0); UNP(v1); UNP(v2); UNP(v3);
  }
  for (; e < e1; ++e) {
    U12 v = yr[(size_t)ce[e] * 32 + l32];
    UNP(v);
  }
#undef UNP
  const float fsc = ni * s * (1.0f / 2047.0f);
  const float boff = 2048.0f * (float)cnt;
  u16x8 o;
#pragma unroll
  for (int c = 0; c < 8; ++c) o[c] = f2b(fsc * ((float)acc[c] - boff));
  *(u16x8*)&As[il][l32 * 8] = o;
  __syncthreads();

  // ---- MFMA phase: wave w covers cols [w*32, w*32+32) of the 16x256 tile ----
  const int r16 = lane & 15, quad = lane >> 4;
  f32x4 acc4[2];
#pragma unroll
  for (int t = 0; t < 2; ++t) acc4[t] = (f32x4){0.f, 0.f, 0.f, 0.f};
  for (int kc = 0; kc < 8; ++kc) {
    bf16x8 af = *(const bf16x8*)&As[r16][kc * 32 + quad * 8];
#pragma unroll
    for (int ct = 0; ct < 2; ++ct) {
      const int n = wave * 32 + ct * 16 + r16;
      bf16x8 bf = *(const bf16x8*)(wbf + (size_t)n * 256 + kc * 32 + quad * 8);
      acc4[ct] = __builtin_amdgcn_mfma_f32_16x16x32_bf16(af, bf, acc4[ct], 0, 0, 0);
    }
  }

  // ---- epilogue: bias + relu + per-graph column max + atomicMax ----
  const int g0 = bg[0], g15 = bg[15];
  if (g0 == g15) {
#pragma unroll
    for (int ct = 0; ct < 2; ++ct) {
      const int col = wave * 32 + ct * 16 + r16;
      const float bias = b1[col];
      float m = 0.f;   // relu identity
#pragma unroll
      for (int r = 0; r < 4; ++r) m = fmaxf(m, acc4[ct][r] + bias);
      m = fmaxf(m, __shfl_xor(m, 16, 64));
      m = fmaxf(m, __shfl_xor(m, 32, 64));
      if (quad == 0) atomicMax(&pooled[g0 * 256 + col], __float_as_int(m));
    }
  } else {
#pragma unroll
    for (int ct = 0; ct < 2; ++ct) {
      const int col = wave * 32 + ct * 16 + r16;
      const float bias = b1[col];
      for (int g = g0; g <= g15; ++g) {
        float m = 0.f;
#pragma unroll
        for (int r = 0; r < 4; ++r) {
          const int row = quad * 4 + r;
          float v = fmaxf(acc4[ct][r] + bias, 0.f);
          if (bg[row] == g) m = fmaxf(m, v);
        }
        m = fmaxf(m, __shfl_xor(m, 16, 64));
        m = fmaxf(m, __shfl_xor(m, 32, 64));
        if (quad == 0) atomicMax(&pooled[g * 256 + col], __float_as_int(m));
      }
    }
  }
}

// ---------------- out = pooled @ W2^T + b2 ----------------
__global__ void k_out(const float* __restrict__ pooled, const float* __restrict__ w2,
                      const float* __restrict__ b2, float* __restrict__ out) {
  const int wave = threadIdx.x >> 6;
  const int lane = threadIdx.x & 63;
  const int g = blockIdx.x * 4 + wave;
  float4 p = ((const float4*)pooled)[g * 64 + lane];
  float4 w = ((const float4*)w2)[lane];
  float s = p.x * w.x + p.y * w.y + p.z * w.z + p.w * w.w;
  for (int off = 32; off; off >>= 1) s += __shfl_down(s, off, 64);
  if (lane == 0) out[g] = s + b2[0];
}

extern "C" void kernel_launch(void* const* d_in, const int* in_sizes, int n_in,
                              void* d_out, int out_size, void* d_ws, size_t ws_size,
                              hipStream_t stream) {
  const float* x     = (const float*)d_in[0];
  const int*   ei    = (const int*)d_in[1];
  const int*   batch = (const int*)d_in[2];
  const float* W1    = (const float*)d_in[3];
  const float* b1    = (const float*)d_in[4];
  const float* W2    = (const float*)d_in[5];
  const float* b2    = (const float*)d_in[6];
  const int* src = ei;
  const int* dst = ei + EE;
  float* out = (float*)d_out;

  // workspace carve (256B aligned)
  size_t off = 0;
  auto carve = [&](size_t bytes) -> void* {
    void* p = (char*)d_ws + off;
    off += (bytes + 255) & ~(size_t)255;
    return p;
  };
  int*   pooled = (int*)carve((size_t)GG * 256 * 4);       // fp32 bit patterns
  int*   gcur   = (int*)carve((size_t)NBK2 * 4);           // bucket counts
  int*   xm     = (int*)carve(4);                          // global y absmax (f32 bits)
  const size_t zlen = off;                                  // one memset covers all 3
  unsigned* y12 = (unsigned*)carve((size_t)NN * 96 * 4);   // int12-packed y rows (384 B)
  int*   pk     = (int*)carve((size_t)NBK2 * BCAP * 4);    // bucket-sorted edges
  int*   csr    = (int*)carve((size_t)NBK2 * BCAP * 4);    // node-grouped dst lists
  int*   ro     = (int*)carve((size_t)NBK2 * 257 * 4);     // per-bucket row offsets
  unsigned short* wbf = (unsigned short*)carve(256 * 256 * 2);

  hipMemsetAsync(pooled, 0, zlen, stream);   // pooled zeros + cursors + xm

  k_split<<<(EE + TT - 1) / TT, 1024, 0, stream>>>(src, dst, gcur, pk);
  k_prep <<<NBK2,               512,  0, stream>>>(gcur, pk, x, W1, wbf, csr, ro, xm);
  k_pack <<<NN / 8,             256,  0, stream>>>(x, ro, xm, y12);
  k_fused4<<<NN / 16,           512,  0, stream>>>(ro, csr, y12, wbf, b1, batch, xm, pooled);
  k_out  <<<GG / 4,             256,  0, stream>>>((const float*)pooled, W2, b2, out);
}